// Round 1
// baseline (6339.575 us; speedup 1.0000x reference)
//
#include <hip/hip_runtime.h>
#include <math.h>

#define NN 50000
#define EE 800000
#define HID 128
#define PED 24
#define IND 64
#define OUTD 64
#define BM 64      // edges per block in edge_kernel
#define LDP 68     // padded LDS row stride (68*4=272 B: 16B-aligned, bank-spread)

__device__ __forceinline__ float gelu_exact(float x) {
    return 0.5f * x * (1.0f + erff(x * 0.70710678118654752440f));
}

// ---------------------------------------------------------------------------
// Kernel 1: xh = x @ W_x + b_x    [N, 128]
// One thread per output element. x rows are L1-hot (128 threads share a row),
// W_x columns are coalesced across threads and fit in L1 (32 KB).
// ---------------------------------------------------------------------------
__global__ __launch_bounds__(256) void xh_kernel(
    const float* __restrict__ x, const float* __restrict__ W_x,
    const float* __restrict__ b_x, float* __restrict__ xh) {
    int gid = blockIdx.x * 256 + threadIdx.x;
    int n = gid >> 7;
    int j = gid & 127;
    if (n >= NN) return;
    const float* xr = x + (size_t)n * IND;
    float acc = b_x[j];
#pragma unroll
    for (int k = 0; k < IND; k++) acc += xr[k] * W_x[k * HID + j];
    xh[(size_t)n * HID + j] = acc;
}

// ---------------------------------------------------------------------------
// Kernel 2: fused edge MLP + gather-multiply + scatter-add.
// Block = 256 threads, BM=64 edges. thread (j = tid&127, h = tid>>7) owns
// hidden channel j for edges [h*32, h*32+32). Hidden state lives in LDS as
// [hid][edge] so the inner e-loop vectorizes to ds_read_b128 broadcasts.
// x0 (residual) is kept in registers. Weights stream from L2 (~3.2 KB/edge
// at BM=64 -> 2.6 GB total, ~75 us at L2 BW).
// ---------------------------------------------------------------------------
__global__ __launch_bounds__(256, 2) void edge_kernel(
    const float* __restrict__ pe_val, const int* __restrict__ pe_idx,
    const float* __restrict__ xh,
    const float* __restrict__ W_in, const float* __restrict__ b_in,
    const float* __restrict__ W1, const float* __restrict__ b1,
    const float* __restrict__ W2, const float* __restrict__ b2,
    const float* __restrict__ Wf, const float* __restrict__ bf,
    float* __restrict__ wV, float* __restrict__ deg) {
    __shared__ float s_act[HID][LDP];   // activation tile, [hid_k][edge]
    __shared__ float s_pe[PED][LDP];    // pe tile, [pe_k][edge]
    __shared__ int s_src[BM];
    __shared__ int s_tgt[BM];

    const int tid = threadIdx.x;
    const int j = tid & 127;
    const int h = tid >> 7;
    const int eh = h * 32;
    const long e0 = (long)blockIdx.x * BM;

    // stage pe tile (transposed) — global side coalesced
    for (int t = tid; t < BM * PED; t += 256) {
        int e = t / PED;
        int k = t - e * PED;
        s_pe[k][e] = pe_val[(size_t)(e0 + e) * PED + k];
    }
    if (tid < BM) {
        s_tgt[tid] = pe_idx[e0 + tid];        // row 0: tgt
        s_src[tid] = pe_idx[EE + e0 + tid];   // row 1: src
    }
    __syncthreads();

    float acc[32], x0sav[32];

    // GEMM1: x0 = pe @ W_in + b_in ; keep x0 in regs, write g(x0) to s_act
    {
        float b = b_in[j];
#pragma unroll
        for (int e = 0; e < 32; e++) acc[e] = b;
        for (int k = 0; k < PED; k++) {
            float w = W_in[k * HID + j];
#pragma unroll
            for (int e = 0; e < 32; e++) acc[e] += s_pe[k][eh + e] * w;
        }
#pragma unroll
        for (int e = 0; e < 32; e++) {
            x0sav[e] = acc[e];
            s_act[j][eh + e] = gelu_exact(acc[e]);
        }
    }
    __syncthreads();

    // GEMM2: h1 = g(x0) @ W1 + b1 ; write g(h1) back to s_act
    {
        float b = b1[j];
#pragma unroll
        for (int e = 0; e < 32; e++) acc[e] = b;
#pragma unroll 4
        for (int k = 0; k < HID; k++) {
            float w = W1[k * HID + j];
#pragma unroll
            for (int e = 0; e < 32; e++) acc[e] += s_act[k][eh + e] * w;
        }
        __syncthreads();  // all reads of s_act done before overwrite
#pragma unroll
        for (int e = 0; e < 32; e++) s_act[j][eh + e] = gelu_exact(acc[e]);
    }
    __syncthreads();

    // GEMM3: h2 = g(h1) @ W2 + b2 ; residual x0' = h2 + x0 ; write to s_act
    {
        float b = b2[j];
#pragma unroll
        for (int e = 0; e < 32; e++) acc[e] = b;
#pragma unroll 4
        for (int k = 0; k < HID; k++) {
            float w = W2[k * HID + j];
#pragma unroll
            for (int e = 0; e < 32; e++) acc[e] += s_act[k][eh + e] * w;
        }
        __syncthreads();
#pragma unroll
        for (int e = 0; e < 32; e++) s_act[j][eh + e] = acc[e] + x0sav[e];
    }
    __syncthreads();

    // GEMM4: score = x0' @ W_fin + b_fin  (stays in regs)
    {
        float b = bf[j];
#pragma unroll
        for (int e = 0; e < 32; e++) acc[e] = b;
#pragma unroll 4
        for (int k = 0; k < HID; k++) {
            float w = Wf[k * HID + j];
#pragma unroll
            for (int e = 0; e < 32; e++) acc[e] += s_act[k][eh + e] * w;
        }
    }

    // epilogue: msg = xh[src] * score ; atomic scatter into wV
#pragma unroll 4
    for (int e = 0; e < 32; e++) {
        int ee = eh + e;
        int src = s_src[ee];
        int tgt = s_tgt[ee];
        float v = xh[(size_t)src * HID + j] * acc[e];
        atomicAdd(&wV[(size_t)tgt * HID + j], v);
    }
    if (tid < BM) atomicAdd(&deg[s_tgt[tid]], 1.0f);
}

// ---------------------------------------------------------------------------
// Kernel 3: out = (wV / max(deg,1) + head_bias) @ W_out + b_out   [N, 64]
// ---------------------------------------------------------------------------
__global__ __launch_bounds__(256) void out_kernel(
    const float* __restrict__ wV, const float* __restrict__ deg,
    const float* __restrict__ head_bias, const float* __restrict__ W_out,
    const float* __restrict__ b_out, float* __restrict__ out) {
    int gid = blockIdx.x * 256 + threadIdx.x;
    int n = gid >> 6;
    int jo = gid & 63;
    if (n >= NN) return;
    float inv = 1.0f / fmaxf(deg[n], 1.0f);
    const float* wr = wV + (size_t)n * HID;
    float acc = b_out[jo];
#pragma unroll
    for (int k = 0; k < HID; k++) {
        float hv = wr[k] * inv + head_bias[k];
        acc += hv * W_out[k * OUTD + jo];
    }
    out[(size_t)n * OUTD + jo] = acc;
}

extern "C" void kernel_launch(void* const* d_in, const int* in_sizes, int n_in,
                              void* d_out, int out_size, void* d_ws, size_t ws_size,
                              hipStream_t stream) {
    const float* x      = (const float*)d_in[0];
    const int*   pe_idx = (const int*)d_in[1];
    const float* pe_val = (const float*)d_in[2];
    const float* W_in   = (const float*)d_in[3];
    const float* b_in   = (const float*)d_in[4];
    const float* W1     = (const float*)d_in[5];
    const float* b1     = (const float*)d_in[6];
    const float* W2     = (const float*)d_in[7];
    const float* b2     = (const float*)d_in[8];
    const float* Wf     = (const float*)d_in[9];
    const float* bf     = (const float*)d_in[10];
    const float* W_x    = (const float*)d_in[11];
    const float* b_x    = (const float*)d_in[12];
    const float* hb     = (const float*)d_in[13];
    const float* W_out  = (const float*)d_in[14];
    const float* b_out  = (const float*)d_in[15];
    float* out = (float*)d_out;

    // workspace layout: xh [N*128] | wV [N*128] | deg [N]   (51.4 MB total)
    float* xh  = (float*)d_ws;
    float* wV  = xh + (size_t)NN * HID;
    float* deg = wV + (size_t)NN * HID;

    // zero the accumulation buffers (ws is poisoned 0xAA before every call)
    hipMemsetAsync(wV, 0, ((size_t)NN * HID + NN) * sizeof(float), stream);

    xh_kernel<<<(NN * HID + 255) / 256, 256, 0, stream>>>(x, W_x, b_x, xh);
    edge_kernel<<<EE / BM, 256, 0, stream>>>(pe_val, pe_idx, xh,
                                             W_in, b_in, W1, b1, W2, b2, Wf, bf,
                                             wV, deg);
    out_kernel<<<(NN * OUTD + 255) / 256, 256, 0, stream>>>(wV, deg, hb, W_out,
                                                            b_out, out);
}

// Round 2
// 2436.627 us; speedup vs baseline: 2.6018x; 2.6018x over previous
//
#include <hip/hip_runtime.h>
#include <math.h>

#define NN 50000
#define EE 800000
#define HID 128
#define PED 24
#define IND 64
#define OUTD 64
#define BME 64      // edges per edge-block
#define ETH 16      // edges per thread
#define JTH 4       // channels per thread
#define LDP 68      // padded e-stride: 68*4=272 B = 17*16 (b128-aligned rows)

__device__ __forceinline__ float gelu_exact(float x) {
    return 0.5f * x * (1.0f + erff(x * 0.70710678118654752440f));
}

// ---------------------------------------------------------------------------
// xh = x @ W_x + b_x    [N, 128]
// ---------------------------------------------------------------------------
__global__ __launch_bounds__(256) void xh_kernel(
    const float* __restrict__ x, const float* __restrict__ W_x,
    const float* __restrict__ b_x, float* __restrict__ xh) {
    int gid = blockIdx.x * 256 + threadIdx.x;
    int n = gid >> 7;
    int j = gid & 127;
    if (n >= NN) return;
    const float* xr = x + (size_t)n * IND;
    float acc = b_x[j];
#pragma unroll
    for (int k = 0; k < IND; k++) acc += xr[k] * W_x[k * HID + j];
    xh[(size_t)n * HID + j] = acc;
}

// ---------------------------------------------------------------------------
// CSR build: histogram(tgt) -> exclusive scan -> scatter edge ids
// ---------------------------------------------------------------------------
__global__ __launch_bounds__(256) void hist_kernel(const int* __restrict__ pe_idx,
                                                   int* __restrict__ cnt) {
    int e = blockIdx.x * 256 + threadIdx.x;
    if (e < EE) atomicAdd(&cnt[pe_idx[e]], 1);
}

__global__ __launch_bounds__(1024) void scan_kernel(const int* __restrict__ cnt,
                                                    int* __restrict__ woff) {
    __shared__ int s_w[16];
    int tid = threadIdx.x;
    const int chunk = (NN + 1023) / 1024;  // 49
    int base = tid * chunk;
    int end = base + chunk; if (end > NN) end = NN;
    int s = 0;
    for (int i = base; i < end; i++) s += cnt[i];
    int v = s;
    int lane = tid & 63, wid = tid >> 6;
#pragma unroll
    for (int d = 1; d < 64; d <<= 1) {
        int u = __shfl_up(v, d, 64);
        if (lane >= d) v += u;
    }
    if (lane == 63) s_w[wid] = v;
    __syncthreads();
    if (tid < 16) {
        int wv = s_w[tid];
#pragma unroll
        for (int d = 1; d < 16; d <<= 1) {
            int u = __shfl_up(wv, d, 64);
            if (tid >= d) wv += u;
        }
        s_w[tid] = wv;
    }
    __syncthreads();
    int exc = v - s + (wid ? s_w[wid - 1] : 0);
    int run = exc;
    for (int i = base; i < end; i++) { woff[i] = run; run += cnt[i]; }
}

__global__ __launch_bounds__(256) void scatter_kernel(const int* __restrict__ pe_idx,
                                                      int* __restrict__ woff,
                                                      int* __restrict__ perm) {
    int e = blockIdx.x * 256 + threadIdx.x;
    if (e < EE) {
        int t = pe_idx[e];
        int p = atomicAdd(&woff[t], 1);
        perm[p] = e;
    }
}

// ---------------------------------------------------------------------------
// Fused edge MLP + gather-multiply + run-reduced scatter (edges CSR-sorted).
// 128 threads, 64 edges. Thread tile = 4 channels x 16 edges: per k it reads
// 16 LDS floats + 1 float4 of weights and does 64 FMAs (0.5 B LDS / FLOP).
// ---------------------------------------------------------------------------
__global__ __launch_bounds__(128) void edge_kernel(
    const float* __restrict__ pe_val, const int* __restrict__ pe_idx,
    const int* __restrict__ perm, const float* __restrict__ xh,
    const float* __restrict__ W_in, const float* __restrict__ b_in,
    const float* __restrict__ W1, const float* __restrict__ b1,
    const float* __restrict__ W2, const float* __restrict__ b2,
    const float* __restrict__ Wf, const float* __restrict__ bf,
    float* __restrict__ wV) {
    __shared__ float s_act[HID][LDP];   // 34.8 KB
    __shared__ float s_pe[PED][LDP];    // 6.5 KB
    __shared__ int s_eid[BME], s_tgt[BME], s_src[BME];

    const int tid = threadIdx.x;
    const int jg = tid >> 2;           // 0..31
    const int eg = tid & 3;            // 0..3
    const int j0 = jg * JTH;
    const int el = eg * ETH;
    const long b0 = (long)blockIdx.x * BME;

    if (tid < BME) {
        int eid = perm[b0 + tid];
        s_eid[tid] = eid;
        s_tgt[tid] = pe_idx[eid];
        s_src[tid] = pe_idx[EE + eid];
    }
    __syncthreads();
    for (int t = tid; t < BME * PED; t += 128) {
        int e = t / PED;
        int k = t - e * PED;
        s_pe[k][e] = pe_val[(size_t)s_eid[e] * PED + k];
    }
    __syncthreads();

    float acc[JTH * ETH], x0s[JTH * ETH];

    // GEMM1: x0 = pe @ W_in + b_in (K=24); keep x0 in regs, write g(x0)
    {
        float4 bb = *(const float4*)&b_in[j0];
        const float* bp = (const float*)&bb;
#pragma unroll
        for (int jj = 0; jj < JTH; jj++)
#pragma unroll
            for (int i = 0; i < ETH; i++) acc[jj * ETH + i] = bp[jj];
#pragma unroll 2
        for (int k = 0; k < PED; k++) {
            float4 w = *(const float4*)&W_in[k * HID + j0];
            const float* wp = (const float*)&w;
            float a[ETH];
#pragma unroll
            for (int i = 0; i < ETH; i++) a[i] = s_pe[k][el + i];
#pragma unroll
            for (int jj = 0; jj < JTH; jj++)
#pragma unroll
                for (int i = 0; i < ETH; i++) acc[jj * ETH + i] += a[i] * wp[jj];
        }
#pragma unroll
        for (int jj = 0; jj < JTH; jj++)
#pragma unroll
            for (int i = 0; i < ETH; i++) {
                float v = acc[jj * ETH + i];
                x0s[jj * ETH + i] = v;
                s_act[j0 + jj][el + i] = gelu_exact(v);
            }
    }
    __syncthreads();

#define GEMM128(Wmat, bvec)                                                    \
    {                                                                          \
        float4 bb = *(const float4*)&(bvec)[j0];                               \
        const float* bp = (const float*)&bb;                                   \
        _Pragma("unroll") for (int jj = 0; jj < JTH; jj++)                     \
            _Pragma("unroll") for (int i = 0; i < ETH; i++)                    \
                acc[jj * ETH + i] = bp[jj];                                    \
        _Pragma("unroll 2") for (int k = 0; k < HID; k++) {                    \
            float4 w = *(const float4*)&(Wmat)[k * HID + j0];                  \
            const float* wp = (const float*)&w;                                \
            float a[ETH];                                                      \
            _Pragma("unroll") for (int i = 0; i < ETH; i++)                    \
                a[i] = s_act[k][el + i];                                       \
            _Pragma("unroll") for (int jj = 0; jj < JTH; jj++)                 \
                _Pragma("unroll") for (int i = 0; i < ETH; i++)                \
                    acc[jj * ETH + i] += a[i] * wp[jj];                        \
        }                                                                      \
    }

    // GEMM2: h1 = g(x0) @ W1 + b1; write g(h1)
    GEMM128(W1, b1);
    __syncthreads();
#pragma unroll
    for (int jj = 0; jj < JTH; jj++)
#pragma unroll
        for (int i = 0; i < ETH; i++)
            s_act[j0 + jj][el + i] = gelu_exact(acc[jj * ETH + i]);
    __syncthreads();

    // GEMM3: h2 = g(h1) @ W2 + b2; residual; write h2 + x0
    GEMM128(W2, b2);
    __syncthreads();
#pragma unroll
    for (int jj = 0; jj < JTH; jj++)
#pragma unroll
        for (int i = 0; i < ETH; i++)
            s_act[j0 + jj][el + i] = acc[jj * ETH + i] + x0s[jj * ETH + i];
    __syncthreads();

    // GEMM4: score = x0' @ W_fin + b_fin (stays in acc)
    GEMM128(Wf, bf);

    // epilogue: msg = xh[src] * score; run-reduce over sorted tgt, then atomic
    {
        float s0 = 0.f, s1 = 0.f, s2 = 0.f, s3 = 0.f;
        int prev = s_tgt[el];
#pragma unroll 4
        for (int i = 0; i < ETH; i++) {
            int e = el + i;
            int tgt = s_tgt[e];
            int src = s_src[e];
            if (tgt != prev) {
                float* wp = &wV[(size_t)prev * HID + j0];
                atomicAdd(wp + 0, s0); atomicAdd(wp + 1, s1);
                atomicAdd(wp + 2, s2); atomicAdd(wp + 3, s3);
                s0 = s1 = s2 = s3 = 0.f;
                prev = tgt;
            }
            float4 xv = *(const float4*)&xh[(size_t)src * HID + j0];
            s0 += xv.x * acc[0 * ETH + i];
            s1 += xv.y * acc[1 * ETH + i];
            s2 += xv.z * acc[2 * ETH + i];
            s3 += xv.w * acc[3 * ETH + i];
        }
        float* wp = &wV[(size_t)prev * HID + j0];
        atomicAdd(wp + 0, s0); atomicAdd(wp + 1, s1);
        atomicAdd(wp + 2, s2); atomicAdd(wp + 3, s3);
    }
#undef GEMM128
}

// ---------------------------------------------------------------------------
// out = (wV / max(deg,1) + head_bias) @ W_out + b_out   [N, 64]
// ---------------------------------------------------------------------------
__global__ __launch_bounds__(256) void out_kernel(
    const float* __restrict__ wV, const int* __restrict__ cnt,
    const float* __restrict__ head_bias, const float* __restrict__ W_out,
    const float* __restrict__ b_out, float* __restrict__ out) {
    int gid = blockIdx.x * 256 + threadIdx.x;
    int n = gid >> 6;
    int jo = gid & 63;
    if (n >= NN) return;
    float inv = 1.0f / fmaxf((float)cnt[n], 1.0f);
    const float* wr = wV + (size_t)n * HID;
    float acc = b_out[jo];
#pragma unroll
    for (int k = 0; k < HID; k++) {
        float hv = wr[k] * inv + head_bias[k];
        acc += hv * W_out[k * OUTD + jo];
    }
    out[(size_t)n * OUTD + jo] = acc;
}

extern "C" void kernel_launch(void* const* d_in, const int* in_sizes, int n_in,
                              void* d_out, int out_size, void* d_ws, size_t ws_size,
                              hipStream_t stream) {
    const float* x      = (const float*)d_in[0];
    const int*   pe_idx = (const int*)d_in[1];
    const float* pe_val = (const float*)d_in[2];
    const float* W_in   = (const float*)d_in[3];
    const float* b_in   = (const float*)d_in[4];
    const float* W1     = (const float*)d_in[5];
    const float* b1     = (const float*)d_in[6];
    const float* W2     = (const float*)d_in[7];
    const float* b2     = (const float*)d_in[8];
    const float* Wf     = (const float*)d_in[9];
    const float* bf     = (const float*)d_in[10];
    const float* W_x    = (const float*)d_in[11];
    const float* b_x    = (const float*)d_in[12];
    const float* hb     = (const float*)d_in[13];
    const float* W_out  = (const float*)d_in[14];
    const float* b_out  = (const float*)d_in[15];
    float* out = (float*)d_out;

    // ws layout: xh [N*128] f32 | wV [N*128] f32 | cnt [N] i32 | woff [N] i32 | perm [E] i32
    float* xh  = (float*)d_ws;
    float* wV  = xh + (size_t)NN * HID;
    int*   cnt = (int*)(wV + (size_t)NN * HID);
    int*   woff = cnt + NN;
    int*   perm = woff + NN;

    // zero wV + cnt (contiguous)
    hipMemsetAsync(wV, 0, ((size_t)NN * HID + NN) * sizeof(float), stream);

    hist_kernel<<<(EE + 255) / 256, 256, 0, stream>>>(pe_idx, cnt);
    scan_kernel<<<1, 1024, 0, stream>>>(cnt, woff);
    scatter_kernel<<<(EE + 255) / 256, 256, 0, stream>>>(pe_idx, woff, perm);

    xh_kernel<<<(NN * HID + 255) / 256, 256, 0, stream>>>(x, W_x, b_x, xh);

    edge_kernel<<<EE / BME, 128, 0, stream>>>(pe_val, pe_idx, perm, xh,
                                              W_in, b_in, W1, b1, W2, b2, Wf, bf,
                                              wV);

    out_kernel<<<(NN * OUTD + 255) / 256, 256, 0, stream>>>(wV, cnt, hb, W_out,
                                                            b_out, out);
}

// Round 3
// 860.233 us; speedup vs baseline: 7.3696x; 2.8325x over previous
//
#include <hip/hip_runtime.h>
#include <math.h>

#define NN 50000
#define EE 800000
#define HID 128
#define PED 24
#define IND 64
#define OUTD 64
#define EBLK 64          // edges per edge-kernel block
#define AKS 136          // act/W LDS k-stride in bf16 (272 B: 16B-aligned, bank-spread)

typedef short bf16x8 __attribute__((ext_vector_type(8)));
typedef float f32x4 __attribute__((ext_vector_type(4)));

__device__ __forceinline__ float gelu_exact(float x) {
    return 0.5f * x * (1.0f + erff(x * 0.70710678118654752440f));
}
__device__ __forceinline__ unsigned short f2bf(float f) {
    unsigned int u = __float_as_uint(f);
    u = (u + 0x7fffu + ((u >> 16) & 1u)) >> 16;   // RNE
    return (unsigned short)u;
}
__device__ __forceinline__ float bf2f(unsigned short s) {
    return __uint_as_float(((unsigned int)s) << 16);
}

// ---------------------------------------------------------------------------
// xh = x @ W_x + b_x    [N, 128]  (fp32, 0.8 GFLOP, trivial)
// ---------------------------------------------------------------------------
__global__ __launch_bounds__(256) void xh_kernel(
    const float* __restrict__ x, const float* __restrict__ W_x,
    const float* __restrict__ b_x, float* __restrict__ xh) {
    int gid = blockIdx.x * 256 + threadIdx.x;
    int n = gid >> 7;
    int j = gid & 127;
    if (n >= NN) return;
    const float* xr = x + (size_t)n * IND;
    float acc = b_x[j];
#pragma unroll
    for (int k = 0; k < IND; k++) acc += xr[k] * W_x[k * HID + j];
    xh[(size_t)n * HID + j] = acc;
}

// ---------------------------------------------------------------------------
// weight prep: bf16 transposed copies WT[j][k] = W[k][j] (A-operand, k-minor)
// ---------------------------------------------------------------------------
__global__ __launch_bounds__(256) void prep_kernel(
    const float* __restrict__ W_in, const float* __restrict__ W1,
    const float* __restrict__ W2, const float* __restrict__ Wf,
    unsigned short* __restrict__ WT_in, unsigned short* __restrict__ WT1,
    unsigned short* __restrict__ WT2, unsigned short* __restrict__ WTf) {
    int idx = blockIdx.x * 256 + threadIdx.x;
    if (idx < 4096) {                       // WT_in [128][32], k>=24 zero-pad
        int j = idx >> 5, k = idx & 31;
        WT_in[idx] = f2bf(k < PED ? W_in[k * HID + j] : 0.f);
    } else if (idx < 4096 + 16384) {
        int i = idx - 4096; int j = i >> 7, k = i & 127;
        WT1[i] = f2bf(W1[k * HID + j]);
    } else if (idx < 4096 + 32768) {
        int i = idx - 4096 - 16384; int j = i >> 7, k = i & 127;
        WT2[i] = f2bf(W2[k * HID + j]);
    } else if (idx < 4096 + 49152) {
        int i = idx - 4096 - 32768; int j = i >> 7, k = i & 127;
        WTf[i] = f2bf(Wf[k * HID + j]);
    }
}

// ---------------------------------------------------------------------------
// CSR build: histogram(tgt) -> exclusive scan -> scatter (perm + src)
// ---------------------------------------------------------------------------
__global__ __launch_bounds__(256) void hist_kernel(const int* __restrict__ pe_idx,
                                                   int* __restrict__ cnt) {
    int e = blockIdx.x * 256 + threadIdx.x;
    if (e < EE) atomicAdd(&cnt[pe_idx[e]], 1);
}

__global__ __launch_bounds__(1024) void scan_kernel(const int* __restrict__ cnt,
                                                    int* __restrict__ woff) {
    __shared__ int s_w[16];
    int tid = threadIdx.x;
    const int chunk = (NN + 1023) / 1024;
    int base = tid * chunk;
    int end = base + chunk; if (end > NN) end = NN;
    int s = 0;
    for (int i = base; i < end; i++) s += cnt[i];
    int v = s;
    int lane = tid & 63, wid = tid >> 6;
#pragma unroll
    for (int d = 1; d < 64; d <<= 1) {
        int u = __shfl_up(v, d, 64);
        if (lane >= d) v += u;
    }
    if (lane == 63) s_w[wid] = v;
    __syncthreads();
    if (tid < 16) {
        int wv = s_w[tid];
#pragma unroll
        for (int d = 1; d < 16; d <<= 1) {
            int u = __shfl_up(wv, d, 64);
            if (tid >= d) wv += u;
        }
        s_w[tid] = wv;
    }
    __syncthreads();
    int exc = v - s + (wid ? s_w[wid - 1] : 0);
    int run = exc;
    for (int i = base; i < end; i++) { woff[i] = run; run += cnt[i]; }
}

__global__ __launch_bounds__(256) void scatter_kernel(const int* __restrict__ pe_idx,
                                                      int* __restrict__ woff,
                                                      int* __restrict__ perm,
                                                      int* __restrict__ srcp) {
    int e = blockIdx.x * 256 + threadIdx.x;
    if (e < EE) {
        int t = pe_idx[e];
        int p = atomicAdd(&woff[t], 1);
        perm[p] = e;
        srcp[p] = pe_idx[EE + e];
    }
}

// ---------------------------------------------------------------------------
// Edge MLP on MFMA. Block = 256 thr (4 waves) x 64 edges.
// D[ch][e]: A = WT (k-minor), B = act[e][k] (k-minor). C layout (16x16x32,
// verified): col = e = lane&15, row = ch = quad*4 + reg  -> writeback packs 4
// consecutive ch as bf16x4 (ds_write_b64) into act[e][ch] for the next GEMM.
// Wave w handles ch-tiles {2w, 2w+1} x all 4 e-tiles.
// ---------------------------------------------------------------------------
__global__ __launch_bounds__(256, 3) void edge_kernel(
    const float* __restrict__ pe_val, const int* __restrict__ perm, int base,
    const unsigned short* __restrict__ WT_in, const unsigned short* __restrict__ WT1,
    const unsigned short* __restrict__ WT2, const unsigned short* __restrict__ WTf,
    const float* __restrict__ b_in, const float* __restrict__ b1,
    const float* __restrict__ b2, const float* __restrict__ bfin,
    unsigned short* __restrict__ g_score) {
    __shared__ unsigned short s_act[EBLK][AKS];   // 17.4 KB
    __shared__ unsigned short s_W[HID][AKS];      // 34.8 KB
    __shared__ int s_eid[EBLK];

    const int tid = threadIdx.x;
    const int lane = tid & 63;
    const int w = tid >> 6;          // wave 0..3
    const int l15 = lane & 15;
    const int quad = lane >> 4;
    const long b0 = (long)base + (long)blockIdx.x * EBLK;

    if (tid < EBLK) s_eid[tid] = perm[b0 + tid];
    // stage W1 (used by GEMM2)
#pragma unroll
    for (int i = 0; i < 8; i++) {
        int idx = tid + i * 256; int r = idx >> 4, seg = idx & 15;
        *(uint4*)&s_W[r][seg * 8] = *(const uint4*)&WT1[r * HID + seg * 8];
    }
    __syncthreads();
    // stage pe (bf16) into act cols 0..31 (24..31 zero)
#pragma unroll
    for (int i = 0; i < 8; i++) {
        int idx = tid + i * 256; int e = idx >> 5, k = idx & 31;
        float v = (k < PED) ? pe_val[(size_t)s_eid[e] * PED + k] : 0.f;
        s_act[e][k] = f2bf(v);
    }
    __syncthreads();

    f32x4 C[2][4];
    f32x4 x0s[2][4];
    const f32x4 z4 = {0.f, 0.f, 0.f, 0.f};

    // ---- GEMM1: x0 = pe @ W_in + b_in   (K=32, one MFMA per tile) ----
    {
        bf16x8 a0 = *(const bf16x8*)&WT_in[((2 * w + 0) * 16 + l15) * 32 + quad * 8];
        bf16x8 a1 = *(const bf16x8*)&WT_in[((2 * w + 1) * 16 + l15) * 32 + quad * 8];
#pragma unroll
        for (int u = 0; u < 4; u++) {
            bf16x8 bfr = *(const bf16x8*)&s_act[u * 16 + l15][quad * 8];
            C[0][u] = __builtin_amdgcn_mfma_f32_16x16x32_bf16(a0, bfr, z4, 0, 0, 0);
            C[1][u] = __builtin_amdgcn_mfma_f32_16x16x32_bf16(a1, bfr, z4, 0, 0, 0);
        }
    }
    __syncthreads();   // act reads done
    // epilogue: +b_in, save x0, gelu -> act
#pragma unroll
    for (int t = 0; t < 2; t++) {
        int ch0 = (2 * w + t) * 16 + quad * 4;
        float4 bb = *(const float4*)&b_in[ch0];
#pragma unroll
        for (int u = 0; u < 4; u++) {
            int e = u * 16 + l15;
            f32x4 c = C[t][u];
            c[0] += bb.x; c[1] += bb.y; c[2] += bb.z; c[3] += bb.w;
            x0s[t][u] = c;
            uint2 p;
            p.x = (unsigned int)f2bf(gelu_exact(c[0])) |
                  ((unsigned int)f2bf(gelu_exact(c[1])) << 16);
            p.y = (unsigned int)f2bf(gelu_exact(c[2])) |
                  ((unsigned int)f2bf(gelu_exact(c[3])) << 16);
            *(uint2*)&s_act[e][ch0] = p;
        }
    }
    __syncthreads();

#define GEMM128()                                                              \
    {                                                                          \
        _Pragma("unroll") for (int t = 0; t < 2; t++)                          \
            _Pragma("unroll") for (int u = 0; u < 4; u++) C[t][u] = z4;        \
        _Pragma("unroll") for (int ks = 0; ks < 4; ks++) {                     \
            bf16x8 a0 = *(const bf16x8*)&s_W[(2 * w + 0) * 16 + l15]           \
                                            [ks * 32 + quad * 8];              \
            bf16x8 a1 = *(const bf16x8*)&s_W[(2 * w + 1) * 16 + l15]           \
                                            [ks * 32 + quad * 8];              \
            _Pragma("unroll") for (int u = 0; u < 4; u++) {                    \
                bf16x8 bfr = *(const bf16x8*)&s_act[u * 16 + l15]              \
                                                   [ks * 32 + quad * 8];       \
                C[0][u] = __builtin_amdgcn_mfma_f32_16x16x32_bf16(a0, bfr,     \
                                                                  C[0][u], 0, 0, 0); \
                C[1][u] = __builtin_amdgcn_mfma_f32_16x16x32_bf16(a1, bfr,     \
                                                                  C[1][u], 0, 0, 0); \
            }                                                                  \
        }                                                                      \
    }

#define STAGE_W(WT)                                                            \
    _Pragma("unroll") for (int i = 0; i < 8; i++) {                            \
        int idx = tid + i * 256; int r = idx >> 4, seg = idx & 15;             \
        *(uint4*)&s_W[r][seg * 8] = *(const uint4*)&(WT)[r * HID + seg * 8];   \
    }

    // ---- GEMM2: h1 = g(x0) @ W1 + b1 ; gelu -> act ; stage W2 ----
    GEMM128();
    __syncthreads();
#pragma unroll
    for (int t = 0; t < 2; t++) {
        int ch0 = (2 * w + t) * 16 + quad * 4;
        float4 bb = *(const float4*)&b1[ch0];
#pragma unroll
        for (int u = 0; u < 4; u++) {
            int e = u * 16 + l15;
            f32x4 c = C[t][u];
            uint2 p;
            p.x = (unsigned int)f2bf(gelu_exact(c[0] + bb.x)) |
                  ((unsigned int)f2bf(gelu_exact(c[1] + bb.y)) << 16);
            p.y = (unsigned int)f2bf(gelu_exact(c[2] + bb.z)) |
                  ((unsigned int)f2bf(gelu_exact(c[3] + bb.w)) << 16);
            *(uint2*)&s_act[e][ch0] = p;
        }
    }
    STAGE_W(WT2);
    __syncthreads();

    // ---- GEMM3: h2 = g(h1) @ W2 + b2 ; x0' = h2 + x0 -> act ; stage Wf ----
    GEMM128();
    __syncthreads();
#pragma unroll
    for (int t = 0; t < 2; t++) {
        int ch0 = (2 * w + t) * 16 + quad * 4;
        float4 bb = *(const float4*)&b2[ch0];
#pragma unroll
        for (int u = 0; u < 4; u++) {
            int e = u * 16 + l15;
            f32x4 c = C[t][u];
            f32x4 x0 = x0s[t][u];
            uint2 p;
            p.x = (unsigned int)f2bf(c[0] + bb.x + x0[0]) |
                  ((unsigned int)f2bf(c[1] + bb.y + x0[1]) << 16);
            p.y = (unsigned int)f2bf(c[2] + bb.z + x0[2]) |
                  ((unsigned int)f2bf(c[3] + bb.w + x0[3]) << 16);
            *(uint2*)&s_act[e][ch0] = p;
        }
    }
    STAGE_W(WTf);
    __syncthreads();

    // ---- GEMM4: score = x0' @ W_fin + b_fin -> act (bf16) ----
    GEMM128();
    __syncthreads();
#pragma unroll
    for (int t = 0; t < 2; t++) {
        int ch0 = (2 * w + t) * 16 + quad * 4;
        float4 bb = *(const float4*)&bfin[ch0];
#pragma unroll
        for (int u = 0; u < 4; u++) {
            int e = u * 16 + l15;
            f32x4 c = C[t][u];
            uint2 p;
            p.x = (unsigned int)f2bf(c[0] + bb.x) |
                  ((unsigned int)f2bf(c[1] + bb.y) << 16);
            p.y = (unsigned int)f2bf(c[2] + bb.z) |
                  ((unsigned int)f2bf(c[3] + bb.w) << 16);
            *(uint2*)&s_act[e][ch0] = p;
        }
    }
    __syncthreads();

    // copy scores to global (coalesced 16B stores), chunk-local position
#pragma unroll
    for (int i = 0; i < 4; i++) {
        int idx = tid + i * 256; int r = idx >> 4, seg = idx & 15;
        *(uint4*)&g_score[((long)blockIdx.x * EBLK + r) * HID + seg * 8] =
            *(const uint4*)&s_act[r][seg * 8];
    }
#undef GEMM128
#undef STAGE_W
}

// ---------------------------------------------------------------------------
// CSR gather-aggregate: wV[n][ch] += sum over row(n) ∩ chunk of
// xh[src]*score. No atomics (chunks are stream-serialized dispatches).
// ---------------------------------------------------------------------------
__global__ __launch_bounds__(256) void agg_kernel(
    const unsigned short* __restrict__ g_score, const int* __restrict__ srcp,
    const int* __restrict__ cnt, const int* __restrict__ woff,
    const float* __restrict__ xh, float* __restrict__ wV, int base, int count) {
    int gid = blockIdx.x * 256 + threadIdx.x;
    int n = gid >> 5;
    int jg = gid & 31;
    if (n >= NN) return;
    int ch0 = jg * 4;
    int end = woff[n];
    int start = end - cnt[n];
    int lo = start > base ? start : base;
    int hi = end < base + count ? end : base + count;
    if (lo >= hi) return;
    float a0 = 0.f, a1 = 0.f, a2 = 0.f, a3 = 0.f;
    for (int p = lo; p < hi; p++) {
        int s = srcp[p];
        float4 xv = *(const float4*)&xh[(size_t)s * HID + ch0];
        uint2 sv = *(const uint2*)&g_score[(size_t)(p - base) * HID + ch0];
        a0 += xv.x * bf2f((unsigned short)(sv.x & 0xffff));
        a1 += xv.y * bf2f((unsigned short)(sv.x >> 16));
        a2 += xv.z * bf2f((unsigned short)(sv.y & 0xffff));
        a3 += xv.w * bf2f((unsigned short)(sv.y >> 16));
    }
    float4* wp = (float4*)&wV[(size_t)n * HID + ch0];
    float4 old = *wp;
    old.x += a0; old.y += a1; old.z += a2; old.w += a3;
    *wp = old;
}

// ---------------------------------------------------------------------------
// out = (wV / max(deg,1) + head_bias) @ W_out + b_out   [N, 64]
// ---------------------------------------------------------------------------
__global__ __launch_bounds__(256) void out_kernel(
    const float* __restrict__ wV, const int* __restrict__ cnt,
    const float* __restrict__ head_bias, const float* __restrict__ W_out,
    const float* __restrict__ b_out, float* __restrict__ out) {
    int gid = blockIdx.x * 256 + threadIdx.x;
    int n = gid >> 6;
    int jo = gid & 63;
    if (n >= NN) return;
    float inv = 1.0f / fmaxf((float)cnt[n], 1.0f);
    const float* wr = wV + (size_t)n * HID;
    float acc = b_out[jo];
#pragma unroll
    for (int k = 0; k < HID; k++) {
        float hv = wr[k] * inv + head_bias[k];
        acc += hv * W_out[k * OUTD + jo];
    }
    out[(size_t)n * OUTD + jo] = acc;
}

extern "C" void kernel_launch(void* const* d_in, const int* in_sizes, int n_in,
                              void* d_out, int out_size, void* d_ws, size_t ws_size,
                              hipStream_t stream) {
    const float* x      = (const float*)d_in[0];
    const int*   pe_idx = (const int*)d_in[1];
    const float* pe_val = (const float*)d_in[2];
    const float* W_in   = (const float*)d_in[3];
    const float* b_in   = (const float*)d_in[4];
    const float* W1     = (const float*)d_in[5];
    const float* b1     = (const float*)d_in[6];
    const float* W2     = (const float*)d_in[7];
    const float* b2     = (const float*)d_in[8];
    const float* Wf     = (const float*)d_in[9];
    const float* bfin   = (const float*)d_in[10];
    const float* W_x    = (const float*)d_in[11];
    const float* b_x    = (const float*)d_in[12];
    const float* hb     = (const float*)d_in[13];
    const float* W_out  = (const float*)d_in[14];
    const float* b_out  = (const float*)d_in[15];
    float* out = (float*)d_out;

    // ws layout (dwords):
    // xh 6.4M | wV 6.4M | cnt 50k | woff 50k | perm 800k | srcp 800k |
    // WT_in 2048 | WT1 8192 | WT2 8192 | WTf 8192 | g_score (rest, bf16)
    float* xh   = (float*)d_ws;
    float* wV   = xh + (size_t)NN * HID;
    int*   cnt  = (int*)(wV + (size_t)NN * HID);
    int*   woff = cnt + NN;
    int*   perm = woff + NN;
    int*   srcp = perm + EE;
    unsigned short* WT_in = (unsigned short*)(srcp + EE);
    unsigned short* WT1   = WT_in + 128 * 32;
    unsigned short* WT2   = WT1 + 128 * 128;
    unsigned short* WTf   = WT2 + 128 * 128;
    unsigned short* g_score = WTf + 128 * 128;

    size_t fixed_bytes = (size_t)((char*)g_score - (char*)d_ws);
    long cap_edges = 0;
    if (ws_size > fixed_bytes)
        cap_edges = (long)((ws_size - fixed_bytes) / (HID * sizeof(unsigned short)));
    long Ec = (cap_edges / 128) * 128;
    if (Ec > EE) Ec = EE;
    if (Ec < 128) Ec = 128;               // last-resort; ws expected ample
    int nch = (int)((EE + Ec - 1) / Ec);

    // zero wV + cnt (contiguous)
    hipMemsetAsync(wV, 0, ((size_t)NN * HID + NN) * sizeof(float), stream);

    hist_kernel<<<(EE + 255) / 256, 256, 0, stream>>>(pe_idx, cnt);
    scan_kernel<<<1, 1024, 0, stream>>>(cnt, woff);
    scatter_kernel<<<(EE + 255) / 256, 256, 0, stream>>>(pe_idx, woff, perm, srcp);
    prep_kernel<<<208, 256, 0, stream>>>(W_in, W1, W2, Wf, WT_in, WT1, WT2, WTf);
    xh_kernel<<<(NN * HID + 255) / 256, 256, 0, stream>>>(x, W_x, b_x, xh);

    for (int c = 0; c < nch; c++) {
        long basec = (long)c * Ec;
        long cntc = EE - basec; if (cntc > Ec) cntc = Ec;
        edge_kernel<<<(int)(cntc / EBLK), 256, 0, stream>>>(
            pe_val, perm, (int)basec, WT_in, WT1, WT2, WTf,
            b_in, b1, b2, bfin, g_score);
        agg_kernel<<<(NN * 32 + 255) / 256, 256, 0, stream>>>(
            g_score, srcp, cnt, woff, xh, wV, (int)basec, (int)cntc);
    }

    out_kernel<<<(NN * OUTD + 255) / 256, 256, 0, stream>>>(wV, cnt, hb, W_out,
                                                            b_out, out);
}